// Round 19
// baseline (377.070 us; speedup 1.0000x reference)
//
#include <hip/hip_runtime.h>

#define HDIM 128

typedef unsigned int uint;
typedef unsigned short ushort;
typedef __attribute__((ext_vector_type(8))) short short8;
typedef __attribute__((ext_vector_type(4))) float f32x4;

typedef __attribute__((address_space(3))) uint  lds_u32_t;
typedef const __attribute__((address_space(1))) uint g_u32_t;
#define GLDS16(gp, lp) __builtin_amdgcn_global_load_lds((g_u32_t*)(gp), (lds_u32_t*)(lp), 16, 0, 0)

// round-to-nearest-even float -> bf16 bits
__device__ inline ushort f2bf(float f) {
    uint u = __float_as_uint(f);
    uint rounding = 0x7fffu + ((u >> 16) & 1u);
    return (ushort)((u + rounding) >> 16);
}
__device__ inline float bf2f(ushort h) { return __uint_as_float(((uint)h) << 16); }

// ======================= CSR build (R16 form) =======================

__global__ __launch_bounds__(256) void k_count(const int* __restrict__ dst,
                                               int* __restrict__ cnt,
                                               int* __restrict__ rank, int e) {
    int i = blockIdx.x * 256 + threadIdx.x;
    if (i < e) rank[i] = atomicAdd(&cnt[dst[i]], 1);
}

__global__ __launch_bounds__(256) void k_dinv(const int* __restrict__ cnt,
                                              float* __restrict__ dinv, int n) {
    int i = blockIdx.x * 256 + threadIdx.x;
    if (i < n) dinv[i] = rsqrtf((float)(cnt[i] + 1));   // +1 self-loop
}

__global__ __launch_bounds__(256) void k_scan1(const int* __restrict__ cnt,
                                               int* __restrict__ offs,
                                               int* __restrict__ bsum, int n) {
    __shared__ int sm[256];
    int tid = threadIdx.x;
    int i = blockIdx.x * 256 + tid;
    int v = (i < n) ? cnt[i] : 0;
    sm[tid] = v;
    __syncthreads();
    for (int off = 1; off < 256; off <<= 1) {
        int t = (tid >= off) ? sm[tid - off] : 0;
        __syncthreads();
        sm[tid] += t;
        __syncthreads();
    }
    if (i < n) offs[i] = sm[tid] - v;
    if (tid == 255) bsum[blockIdx.x] = sm[255];
}

__global__ __launch_bounds__(512) void k_scan2(int* __restrict__ bsum, int nb) {
    __shared__ int sm[512];
    int tid = threadIdx.x;
    int v = (tid < nb) ? bsum[tid] : 0;
    sm[tid] = v;
    __syncthreads();
    for (int off = 1; off < 512; off <<= 1) {
        int t = (tid >= off) ? sm[tid - off] : 0;
        __syncthreads();
        sm[tid] += t;
        __syncthreads();
    }
    if (tid < nb) bsum[tid] = sm[tid] - v;
}

__global__ __launch_bounds__(256) void k_scan3(int* __restrict__ offs,
                                               const int* __restrict__ bsum,
                                               int n, int e) {
    int i = blockIdx.x * 256 + threadIdx.x;
    if (i < n) offs[i] += bsum[blockIdx.x];
    if (i == 0) offs[n] = e;
}

__global__ __launch_bounds__(256) void k_fill(const int* __restrict__ src,
                                              const int* __restrict__ dst,
                                              const int* __restrict__ offs,
                                              const int* __restrict__ rank,
                                              int* __restrict__ csr, int e) {
    int i = blockIdx.x * 256 + threadIdx.x;
    if (i < e) {
        csr[offs[dst[i]] + rank[i]] = src[i];
    }
}

// ===== W prep: transpose W[K][128] -> tile-major bf16 plane [K/32][128][32] (linear) =====

__global__ __launch_bounds__(256) void k_prep_w(const float* __restrict__ W,
                                                ushort* __restrict__ wt, int K) {
    int idx = blockIdx.x * 256 + threadIdx.x;
    if (idx < K * HDIM) {
        int k = idx >> 7;       // k index (row in W)
        int c = idx & 127;      // output col
        wt[(k >> 5) * 4096 + c * 32 + (k & 31)] = f2bf(W[idx]);
    }
}

// ===== layer-1 GEMM: X = fp32 [n][256] direct, bf16-converted in-register; W in LDS =====

__global__ __launch_bounds__(512)
void k_mm_f32(const float* __restrict__ X,
              const ushort* __restrict__ WP,
              const float* __restrict__ dinv,
              ushort* __restrict__ g, int n)
{
    __shared__ ushort w[8 * 4096];

    const int tid  = threadIdx.x;
    const int wv   = tid >> 6;
    const int lane = tid & 63;
    const int r    = lane & 15;
    const int gq   = lane >> 4;

    #pragma unroll
    for (int i = 0; i < 8; i++) {
        int off = (i * 512 + tid) * 8;
        GLDS16(WP + off, w + off);
    }

    const int tile   = blockIdx.x * 8 + wv;
    const int ntiles = (n + 15) / 16;
    const bool twork = tile < ntiles;
    int rowr = twork ? tile * 16 + r : 0;
    const bool rok = twork && (rowr < n);
    if (twork && rowr >= n) rowr = n - 1;

    f32x4 xf[16];
    if (twork) {
        const f32x4* xp = (const f32x4*)(X + (size_t)rowr * 256);
        #pragma unroll
        for (int kt = 0; kt < 8; kt++) {
            xf[kt * 2]     = xp[kt * 8 + gq * 2];
            xf[kt * 2 + 1] = xp[kt * 8 + gq * 2 + 1];
        }
    }

    __syncthreads();   // drains W glds + X loads

    if (!twork) return;

    f32x4 acc[8];
    #pragma unroll
    for (int m = 0; m < 8; m++) acc[m] = (f32x4){0.f, 0.f, 0.f, 0.f};

    #pragma unroll
    for (int kt = 0; kt < 8; kt++) {
        float v[8] = {xf[kt*2][0], xf[kt*2][1], xf[kt*2][2], xf[kt*2][3],
                      xf[kt*2+1][0], xf[kt*2+1][1], xf[kt*2+1][2], xf[kt*2+1][3]};
        short8 bh;
        #pragma unroll
        for (int q = 0; q < 8; q++) bh[q] = (short)f2bf(v[q]);
        #pragma unroll
        for (int m = 0; m < 8; m++) {
            short8 wf = *(const short8*)&w[kt * 4096 + (m * 16 + r) * 32 + gq * 8];
            acc[m] = __builtin_amdgcn_mfma_f32_16x16x32_bf16(wf, bh, acc[m], 0, 0, 0);
        }
    }

    if (rok) {
        float di = dinv[rowr];
        #pragma unroll
        for (int m = 0; m < 8; m++) {
            f32x4 a = acc[m];
            uint2 pk;
            pk.x = (uint)f2bf(a[0] * di) | ((uint)f2bf(a[1] * di) << 16);
            pk.y = (uint)f2bf(a[2] * di) | ((uint)f2bf(a[3] * di) << 16);
            *(uint2*)(g + (size_t)rowr * HDIM + m * 16 + gq * 4) = pk;
        }
    }
}

// ===== FUSED gather+mm: g_out = bf16( dinv .* ( relu(dinv*(sum g_in)+b) @ W ) ) =====
// Per block: W (32KB) staged via glds. Per wave: gather 16 nodes (16 lanes/node,
// 4 rounds of 4 nodes), write activation rows bf16 into per-wave LDS xb laid out
// FRAGMENT-MAJOR [unit][row] so mm-phase ds_read_b128 is contiguous-1KB
// conflict-free. Then MFMA against W-LDS, store g_out row-major with dinv.

__global__ __launch_bounds__(512)
void k_gmm(const ushort* __restrict__ g_in,
           const int* __restrict__ csr,
           const int* __restrict__ offs,
           const float* __restrict__ dinv,
           const float* __restrict__ bias,
           const ushort* __restrict__ WP,
           ushort* __restrict__ g_out, int n)
{
    __shared__ ushort w[4 * 4096];        // 32KB W plane
    __shared__ ushort xb[8][16][128];     // 32KB: [wave][unit(16B)][row*8]

    const int tid  = threadIdx.x;
    const int wv   = tid >> 6;
    const int lane = tid & 63;

    // stage W (linear)
    #pragma unroll
    for (int i = 0; i < 4; i++) {
        int off = (i * 512 + tid) * 8;
        GLDS16(WP + off, w + off);
    }

    const int tile   = blockIdx.x * 8 + wv;
    const int ntiles = (n + 15) / 16;
    const bool twork = tile < ntiles;

    // ---- gather phase: 4 rounds x 4 nodes; 16 lanes per node ----
    const int c16 = lane & 15;            // covers cols c16*8 .. +7
    const int g4  = lane >> 4;
    if (twork) {
        #pragma unroll
        for (int s = 0; s < 4; s++) {
            int row  = s * 4 + g4;        // 0..15 within tile
            int node = tile * 16 + row;
            float a0 = 0.f, a1 = 0.f, a2 = 0.f, a3 = 0.f,
                  a4 = 0.f, a5 = 0.f, a6 = 0.f, a7 = 0.f;
            if (node < n) {
                auto ACC = [&](uint4 u) {
                    a0 += bf2f((ushort)(u.x & 0xffff)); a1 += bf2f((ushort)(u.x >> 16));
                    a2 += bf2f((ushort)(u.y & 0xffff)); a3 += bf2f((ushort)(u.y >> 16));
                    a4 += bf2f((ushort)(u.z & 0xffff)); a5 += bf2f((ushort)(u.z >> 16));
                    a6 += bf2f((ushort)(u.w & 0xffff)); a7 += bf2f((ushort)(u.w >> 16));
                };
                int e0 = offs[node];
                int e1 = offs[node + 1];
                ACC(*(const uint4*)(g_in + (size_t)node * HDIM + c16 * 8));  // self
                int e = e0;
                for (; e + 4 <= e1; e += 4) {
                    int s0 = csr[e], s1 = csr[e + 1], s2 = csr[e + 2], s3 = csr[e + 3];
                    uint4 v0 = *(const uint4*)(g_in + (size_t)s0 * HDIM + c16 * 8);
                    uint4 v1 = *(const uint4*)(g_in + (size_t)s1 * HDIM + c16 * 8);
                    uint4 v2 = *(const uint4*)(g_in + (size_t)s2 * HDIM + c16 * 8);
                    uint4 v3 = *(const uint4*)(g_in + (size_t)s3 * HDIM + c16 * 8);
                    ACC(v0); ACC(v1); ACC(v2); ACC(v3);
                }
                for (; e < e1; e++) {
                    int ss = csr[e];
                    ACC(*(const uint4*)(g_in + (size_t)ss * HDIM + c16 * 8));
                }
                float di = dinv[node];
                float4 b0 = *(const float4*)(bias + c16 * 8);
                float4 b1 = *(const float4*)(bias + c16 * 8 + 4);
                a0 = fmaxf(fmaf(di, a0, b0.x), 0.f); a1 = fmaxf(fmaf(di, a1, b0.y), 0.f);
                a2 = fmaxf(fmaf(di, a2, b0.z), 0.f); a3 = fmaxf(fmaf(di, a3, b0.w), 0.f);
                a4 = fmaxf(fmaf(di, a4, b1.x), 0.f); a5 = fmaxf(fmaf(di, a5, b1.y), 0.f);
                a6 = fmaxf(fmaf(di, a6, b1.z), 0.f); a7 = fmaxf(fmaf(di, a7, b1.w), 0.f);
            }
            uint4 ph;
            ph.x = (uint)f2bf(a0) | ((uint)f2bf(a1) << 16);
            ph.y = (uint)f2bf(a2) | ((uint)f2bf(a3) << 16);
            ph.z = (uint)f2bf(a4) | ((uint)f2bf(a5) << 16);
            ph.w = (uint)f2bf(a6) | ((uint)f2bf(a7) << 16);
            *(uint4*)&xb[wv][c16][row * 8] = ph;   // fragment-major: unit=c16, row
        }
    }

    __syncthreads();   // drains W glds (+ per-wave xb writes)

    if (!twork) return;

    // ---- mm phase: B-fragments from xb (contiguous 1KB per instr) ----
    const int r  = lane & 15;
    const int gq = lane >> 4;

    short8 xc[4];
    #pragma unroll
    for (int kt = 0; kt < 4; kt++)
        xc[kt] = *(const short8*)&xb[wv][kt * 4 + gq][r * 8];

    f32x4 acc[8];
    #pragma unroll
    for (int m = 0; m < 8; m++) acc[m] = (f32x4){0.f, 0.f, 0.f, 0.f};

    #pragma unroll
    for (int kt = 0; kt < 4; kt++) {
        #pragma unroll
        for (int m = 0; m < 8; m++) {
            short8 wf = *(const short8*)&w[kt * 4096 + (m * 16 + r) * 32 + gq * 8];
            acc[m] = __builtin_amdgcn_mfma_f32_16x16x32_bf16(wf, xc[kt], acc[m], 0, 0, 0);
        }
    }

    int rowr = tile * 16 + r;
    if (rowr < n) {
        float di = dinv[rowr];
        #pragma unroll
        for (int m = 0; m < 8; m++) {
            f32x4 a = acc[m];
            uint2 pk;
            pk.x = (uint)f2bf(a[0] * di) | ((uint)f2bf(a[1] * di) << 16);
            pk.y = (uint)f2bf(a[2] * di) | ((uint)f2bf(a[3] * di) << 16);
            *(uint2*)(g_out + (size_t)rowr * HDIM + m * 16 + gq * 4) = pk;
        }
    }
}

// ===== final gather: out = dinv*(g[d] + sum g[src]) + b (fp32, no relu) =====
// 16 lanes/node, uint4 per lane. g row-major [n][128] bf16.

__global__ __launch_bounds__(256) void k_gather_out(const ushort* __restrict__ g,
                                                    const int* __restrict__ csr,
                                                    const int* __restrict__ offs,
                                                    const float* __restrict__ dinv,
                                                    const float* __restrict__ bias,
                                                    float* __restrict__ out, int n)
{
    int t    = blockIdx.x * 256 + threadIdx.x;
    int node = t >> 4;
    int l    = t & 15;
    if (node >= n) return;

    int e0 = offs[node];
    int e1 = offs[node + 1];

    float a0 = 0.f, a1 = 0.f, a2 = 0.f, a3 = 0.f,
          a4 = 0.f, a5 = 0.f, a6 = 0.f, a7 = 0.f;

    auto ACC = [&](uint4 u) {
        a0 += bf2f((ushort)(u.x & 0xffff)); a1 += bf2f((ushort)(u.x >> 16));
        a2 += bf2f((ushort)(u.y & 0xffff)); a3 += bf2f((ushort)(u.y >> 16));
        a4 += bf2f((ushort)(u.z & 0xffff)); a5 += bf2f((ushort)(u.z >> 16));
        a6 += bf2f((ushort)(u.w & 0xffff)); a7 += bf2f((ushort)(u.w >> 16));
    };

    ACC(*(const uint4*)(g + (size_t)node * HDIM + l * 8));   // self

    int e = e0;
    for (; e + 4 <= e1; e += 4) {
        int s0 = csr[e], s1 = csr[e + 1], s2 = csr[e + 2], s3 = csr[e + 3];
        uint4 v0 = *(const uint4*)(g + (size_t)s0 * HDIM + l * 8);
        uint4 v1 = *(const uint4*)(g + (size_t)s1 * HDIM + l * 8);
        uint4 v2 = *(const uint4*)(g + (size_t)s2 * HDIM + l * 8);
        uint4 v3 = *(const uint4*)(g + (size_t)s3 * HDIM + l * 8);
        ACC(v0); ACC(v1); ACC(v2); ACC(v3);
    }
    for (; e < e1; e++) {
        int s = csr[e];
        ACC(*(const uint4*)(g + (size_t)s * HDIM + l * 8));
    }

    float di = dinv[node];
    float4 b0 = *(const float4*)(bias + l * 8);
    float4 b1 = *(const float4*)(bias + l * 8 + 4);
    float4 w0 = make_float4(fmaf(di, a0, b0.x), fmaf(di, a1, b0.y),
                            fmaf(di, a2, b0.z), fmaf(di, a3, b0.w));
    float4 w1 = make_float4(fmaf(di, a4, b1.x), fmaf(di, a5, b1.y),
                            fmaf(di, a6, b1.z), fmaf(di, a7, b1.w));
    *(float4*)(out + (size_t)node * HDIM + l * 8)     = w0;
    *(float4*)(out + (size_t)node * HDIM + l * 8 + 4) = w1;
}

// ======================= launch =======================

extern "C" void kernel_launch(void* const* d_in, const int* in_sizes, int n_in,
                              void* d_out, int out_size, void* d_ws, size_t ws_size,
                              hipStream_t stream)
{
    const float* x  = (const float*)d_in[0];
    const int*   ei = (const int*)d_in[1];
    const float* W1 = (const float*)d_in[2];
    const float* b1 = (const float*)d_in[3];
    const float* W2 = (const float*)d_in[4];
    const float* b2 = (const float*)d_in[5];
    const float* W3 = (const float*)d_in[6];
    const float* b3 = (const float*)d_in[7];
    float* out = (float*)d_out;

    const int n = in_sizes[0] / 256;   // IN = 256
    const int E = in_sizes[1] / 2;
    const int* src = ei;
    const int* dst = ei + E;

    // workspace layout (bytes):
    //   dinv @0, cnt @512K, offs @1M, bsum @1.5M, csr @1600K (6.4MB),
    //   rank @8M (6.4MB), wt @14.5M (64KB slot),
    //   g1 @16M (25.7MB), g2 @42M (25.7MB), g3 @68M (25.7MB)
    char*   ws   = (char*)d_ws;
    float*  dinv = (float*)(ws);
    int*    cnt  = (int*)(ws + (512 << 10));
    int*    offs = (int*)(ws + (1 << 20));
    int*    bsum = (int*)(ws + 1536 * 1024);
    int*    csr  = (int*)(ws + 1600 * 1024);
    int*    rank = (int*)(ws + (size_t)(8 << 20));
    ushort* wt   = (ushort*)(ws + 14848 * 1024);
    ushort* g1   = (ushort*)(ws + (size_t)(16 << 20));
    ushort* g2   = (ushort*)(ws + (size_t)(42 << 20));
    ushort* g3   = (ushort*)(ws + (size_t)(68 << 20));

    dim3 blk(256);
    int ngrid = (n + 255) / 256;
    int egrid = (E + 255) / 256;

    // ---- CSR build + norms ----
    hipMemsetAsync(cnt, 0, (size_t)n * 4, stream);
    k_count<<<egrid, blk, 0, stream>>>(dst, cnt, rank, E);
    k_dinv<<<ngrid, blk, 0, stream>>>(cnt, dinv, n);
    k_scan1<<<ngrid, blk, 0, stream>>>(cnt, offs, bsum, n);
    k_scan2<<<1, 512, 0, stream>>>(bsum, ngrid);
    k_scan3<<<ngrid, blk, 0, stream>>>(offs, bsum, n, E);
    k_fill<<<egrid, blk, 0, stream>>>(src, dst, offs, rank, csr, E);

    int ntiles   = (n + 15) / 16;
    int mm_grid  = (ntiles + 7) / 8;
    int gat_grid = (int)(((size_t)n * 16 + 255) / 256);

    // layer 1 (K=256, fp32 x direct; W in LDS)
    k_prep_w<<<(256 * HDIM + 255) / 256, blk, 0, stream>>>(W1, wt, 256);
    k_mm_f32<<<mm_grid, 512, 0, stream>>>(x, wt, dinv, g1, n);
    // fused gather1(relu) + mm2
    k_prep_w<<<(128 * HDIM + 255) / 256, blk, 0, stream>>>(W2, wt, 128);
    k_gmm<<<mm_grid, 512, 0, stream>>>(g1, csr, offs, dinv, b1, wt, g2, n);
    // fused gather2(relu) + mm3
    k_prep_w<<<(128 * HDIM + 255) / 256, blk, 0, stream>>>(W3, wt, 128);
    k_gmm<<<mm_grid, 512, 0, stream>>>(g2, csr, offs, dinv, b2, wt, g3, n);
    // final gather (fp32 out, no relu)
    k_gather_out<<<gat_grid, blk, 0, stream>>>(g3, csr, offs, dinv, b3, out, n);
}

// Round 20
// 356.987 us; speedup vs baseline: 1.0563x; 1.0563x over previous
//
#include <hip/hip_runtime.h>

#define HDIM 128

typedef unsigned int uint;
typedef unsigned short ushort;
typedef __attribute__((ext_vector_type(8))) short short8;
typedef __attribute__((ext_vector_type(4))) float f32x4;

typedef __attribute__((address_space(3))) uint  lds_u32_t;
typedef const __attribute__((address_space(1))) uint g_u32_t;
#define GLDS16(gp, lp) __builtin_amdgcn_global_load_lds((g_u32_t*)(gp), (lds_u32_t*)(lp), 16, 0, 0)

// round-to-nearest-even float -> bf16 bits
__device__ inline ushort f2bf(float f) {
    uint u = __float_as_uint(f);
    uint rounding = 0x7fffu + ((u >> 16) & 1u);
    return (ushort)((u + rounding) >> 16);
}
__device__ inline float bf2f(ushort h) { return __uint_as_float(((uint)h) << 16); }

// ======================= CSR build =======================

__global__ __launch_bounds__(256) void k_count(const int* __restrict__ dst,
                                               int* __restrict__ cnt,
                                               int* __restrict__ rank, int e) {
    int i = blockIdx.x * 256 + threadIdx.x;
    if (i < e) rank[i] = atomicAdd(&cnt[dst[i]], 1);
}

// scan1 + dinv fused (cnt already in-flight here)
__global__ __launch_bounds__(256) void k_scan1(const int* __restrict__ cnt,
                                               int* __restrict__ offs,
                                               int* __restrict__ bsum,
                                               float* __restrict__ dinv, int n) {
    __shared__ int sm[256];
    int tid = threadIdx.x;
    int i = blockIdx.x * 256 + tid;
    int v = (i < n) ? cnt[i] : 0;
    sm[tid] = v;
    __syncthreads();
    for (int off = 1; off < 256; off <<= 1) {
        int t = (tid >= off) ? sm[tid - off] : 0;
        __syncthreads();
        sm[tid] += t;
        __syncthreads();
    }
    if (i < n) {
        offs[i] = sm[tid] - v;
        dinv[i] = rsqrtf((float)(v + 1));   // +1 self-loop
    }
    if (tid == 255) bsum[blockIdx.x] = sm[255];
}

__global__ __launch_bounds__(512) void k_scan2(int* __restrict__ bsum, int nb) {
    __shared__ int sm[512];
    int tid = threadIdx.x;
    int v = (tid < nb) ? bsum[tid] : 0;
    sm[tid] = v;
    __syncthreads();
    for (int off = 1; off < 512; off <<= 1) {
        int t = (tid >= off) ? sm[tid - off] : 0;
        __syncthreads();
        sm[tid] += t;
        __syncthreads();
    }
    if (tid < nb) bsum[tid] = sm[tid] - v;
}

__global__ __launch_bounds__(256) void k_scan3(int* __restrict__ offs,
                                               const int* __restrict__ bsum,
                                               int n, int e) {
    int i = blockIdx.x * 256 + threadIdx.x;
    if (i < n) offs[i] += bsum[blockIdx.x];
    if (i == 0) offs[n] = e;
}

__global__ __launch_bounds__(256) void k_fill(const int* __restrict__ src,
                                              const int* __restrict__ dst,
                                              const int* __restrict__ offs,
                                              const int* __restrict__ rank,
                                              int* __restrict__ csr, int e) {
    int i = blockIdx.x * 256 + threadIdx.x;
    if (i < e) {
        csr[offs[dst[i]] + rank[i]] = src[i];
    }
}

// ===== W prep: transpose W[K][128] -> tile-major bf16 plane [K/32][128][32] (linear) =====

__global__ __launch_bounds__(256) void k_prep_w(const float* __restrict__ W,
                                                ushort* __restrict__ wt, int K) {
    int idx = blockIdx.x * 256 + threadIdx.x;
    if (idx < K * HDIM) {
        int k = idx >> 7;       // k index (row in W)
        int c = idx & 127;      // output col
        wt[(k >> 5) * 4096 + c * 32 + (k & 31)] = f2bf(W[idx]);
    }
}

// =============== MFMA GEMM: g = bf16( dinv .* (X @ W) ) ===============
// W staged ONCE per block into LDS; one barrier; X direct-to-register.
// 16 rows/wave; pure bf16; g row-major [n][128].

template<int NKT>
__global__ __launch_bounds__(512)
void k_mm(const ushort* __restrict__ XP,
          const ushort* __restrict__ WP,
          const float* __restrict__ dinv,
          ushort* __restrict__ g, int n)
{
    __shared__ ushort w[NKT * 4096];

    const int tid  = threadIdx.x;
    const int wv   = tid >> 6;
    const int lane = tid & 63;
    const int r    = lane & 15;
    const int gq   = lane >> 4;

    #pragma unroll
    for (int i = 0; i < NKT; i++) {
        int off = (i * 512 + tid) * 8;
        GLDS16(WP + off, w + off);
    }

    const int tile   = blockIdx.x * 8 + wv;
    const int ntiles = (n + 15) / 16;
    const bool twork = tile < ntiles;
    int rowr = twork ? tile * 16 + r : 0;
    const bool rok = twork && (rowr < n);
    if (twork && rowr >= n) rowr = n - 1;

    const size_t n32 = (size_t)n * 32;

    short8 xc[NKT];
    if (twork) {
        const size_t ro = (size_t)rowr * 32 + gq * 8;
        #pragma unroll
        for (int kt = 0; kt < NKT; kt++)
            xc[kt] = *(const short8*)(XP + kt * n32 + ro);
    }

    __syncthreads();   // drains W glds + X loads in one bulk wait

    if (!twork) return;

    f32x4 acc[8];
    #pragma unroll
    for (int m = 0; m < 8; m++) acc[m] = (f32x4){0.f, 0.f, 0.f, 0.f};

    #pragma unroll
    for (int kt = 0; kt < NKT; kt++) {
        #pragma unroll
        for (int m = 0; m < 8; m++) {
            short8 wf = *(const short8*)&w[kt * 4096 + (m * 16 + r) * 32 + gq * 8];
            acc[m] = __builtin_amdgcn_mfma_f32_16x16x32_bf16(wf, xc[kt], acc[m], 0, 0, 0);
        }
    }

    if (rok) {
        float di = dinv[rowr];
        #pragma unroll
        for (int m = 0; m < 8; m++) {
            f32x4 a = acc[m];
            uint2 pk;
            pk.x = (uint)f2bf(a[0] * di) | ((uint)f2bf(a[1] * di) << 16);
            pk.y = (uint)f2bf(a[2] * di) | ((uint)f2bf(a[3] * di) << 16);
            *(uint2*)(g + (size_t)rowr * HDIM + m * 16 + gq * 4) = pk;
        }
    }
}

// ===== layer-1 GEMM: X = fp32 [n][256] direct, bf16-converted in-register; W in LDS =====

__global__ __launch_bounds__(512)
void k_mm_f32(const float* __restrict__ X,
              const ushort* __restrict__ WP,
              const float* __restrict__ dinv,
              ushort* __restrict__ g, int n)
{
    __shared__ ushort w[8 * 4096];

    const int tid  = threadIdx.x;
    const int wv   = tid >> 6;
    const int lane = tid & 63;
    const int r    = lane & 15;
    const int gq   = lane >> 4;

    #pragma unroll
    for (int i = 0; i < 8; i++) {
        int off = (i * 512 + tid) * 8;
        GLDS16(WP + off, w + off);
    }

    const int tile   = blockIdx.x * 8 + wv;
    const int ntiles = (n + 15) / 16;
    const bool twork = tile < ntiles;
    int rowr = twork ? tile * 16 + r : 0;
    const bool rok = twork && (rowr < n);
    if (twork && rowr >= n) rowr = n - 1;

    f32x4 xf[16];
    if (twork) {
        const f32x4* xp = (const f32x4*)(X + (size_t)rowr * 256);
        #pragma unroll
        for (int kt = 0; kt < 8; kt++) {
            xf[kt * 2]     = xp[kt * 8 + gq * 2];
            xf[kt * 2 + 1] = xp[kt * 8 + gq * 2 + 1];
        }
    }

    __syncthreads();   // drains W glds + X loads

    if (!twork) return;

    f32x4 acc[8];
    #pragma unroll
    for (int m = 0; m < 8; m++) acc[m] = (f32x4){0.f, 0.f, 0.f, 0.f};

    #pragma unroll
    for (int kt = 0; kt < 8; kt++) {
        float v[8] = {xf[kt*2][0], xf[kt*2][1], xf[kt*2][2], xf[kt*2][3],
                      xf[kt*2+1][0], xf[kt*2+1][1], xf[kt*2+1][2], xf[kt*2+1][3]};
        short8 bh;
        #pragma unroll
        for (int q = 0; q < 8; q++) bh[q] = (short)f2bf(v[q]);
        #pragma unroll
        for (int m = 0; m < 8; m++) {
            short8 wf = *(const short8*)&w[kt * 4096 + (m * 16 + r) * 32 + gq * 8];
            acc[m] = __builtin_amdgcn_mfma_f32_16x16x32_bf16(wf, bh, acc[m], 0, 0, 0);
        }
    }

    if (rok) {
        float di = dinv[rowr];
        #pragma unroll
        for (int m = 0; m < 8; m++) {
            f32x4 a = acc[m];
            uint2 pk;
            pk.x = (uint)f2bf(a[0] * di) | ((uint)f2bf(a[1] * di) << 16);
            pk.y = (uint)f2bf(a[2] * di) | ((uint)f2bf(a[3] * di) << 16);
            *(uint2*)(g + (size_t)rowr * HDIM + m * 16 + gq * 4) = pk;
        }
    }
}

// ===== gather + finish: o = [relu](dinv*(g[d] + sum g[src]) + b) =====
// 16 lanes/node (uint4 = 8 bf16/lane) -> 4 nodes per wave.
// g row-major [n][128] bf16. EMIT_PLANE: tile-major [4][n][32] bf16 plane.

template<bool RELU, bool EMIT_PLANE>
__global__ __launch_bounds__(256) void k_gather(const ushort* __restrict__ g,
                                                const int* __restrict__ csr,
                                                const int* __restrict__ offs,
                                                const float* __restrict__ dinv,
                                                const float* __restrict__ bias,
                                                float* __restrict__ out,
                                                ushort* __restrict__ ap, int n)
{
    int t    = blockIdx.x * 256 + threadIdx.x;
    int node = t >> 4;
    int l    = t & 15;          // lane covers cols l*8 .. l*8+7
    if (node >= n) return;

    int e0 = offs[node];
    int e1 = offs[node + 1];

    float a0 = 0.f, a1 = 0.f, a2 = 0.f, a3 = 0.f,
          a4 = 0.f, a5 = 0.f, a6 = 0.f, a7 = 0.f;

    auto ACC = [&](uint4 u) {
        a0 += bf2f((ushort)(u.x & 0xffff)); a1 += bf2f((ushort)(u.x >> 16));
        a2 += bf2f((ushort)(u.y & 0xffff)); a3 += bf2f((ushort)(u.y >> 16));
        a4 += bf2f((ushort)(u.z & 0xffff)); a5 += bf2f((ushort)(u.z >> 16));
        a6 += bf2f((ushort)(u.w & 0xffff)); a7 += bf2f((ushort)(u.w >> 16));
    };

    // self-loop
    ACC(*(const uint4*)(g + (size_t)node * HDIM + l * 8));

    int e = e0;
    for (; e + 4 <= e1; e += 4) {
        int s0 = csr[e], s1 = csr[e + 1], s2 = csr[e + 2], s3 = csr[e + 3];
        uint4 v0 = *(const uint4*)(g + (size_t)s0 * HDIM + l * 8);
        uint4 v1 = *(const uint4*)(g + (size_t)s1 * HDIM + l * 8);
        uint4 v2 = *(const uint4*)(g + (size_t)s2 * HDIM + l * 8);
        uint4 v3 = *(const uint4*)(g + (size_t)s3 * HDIM + l * 8);
        ACC(v0); ACC(v1); ACC(v2); ACC(v3);
    }
    for (; e < e1; e++) {
        int s = csr[e];
        ACC(*(const uint4*)(g + (size_t)s * HDIM + l * 8));
    }

    float di = dinv[node];
    float4 b0 = *(const float4*)(bias + l * 8);
    float4 b1 = *(const float4*)(bias + l * 8 + 4);
    float o0 = fmaf(di, a0, b0.x), o1 = fmaf(di, a1, b0.y);
    float o2 = fmaf(di, a2, b0.z), o3 = fmaf(di, a3, b0.w);
    float o4 = fmaf(di, a4, b1.x), o5 = fmaf(di, a5, b1.y);
    float o6 = fmaf(di, a6, b1.z), o7 = fmaf(di, a7, b1.w);
    if (RELU) {
        o0 = fmaxf(o0, 0.f); o1 = fmaxf(o1, 0.f); o2 = fmaxf(o2, 0.f); o3 = fmaxf(o3, 0.f);
        o4 = fmaxf(o4, 0.f); o5 = fmaxf(o5, 0.f); o6 = fmaxf(o6, 0.f); o7 = fmaxf(o7, 0.f);
    }
    if (EMIT_PLANE) {
        uint4 ph;
        ph.x = (uint)f2bf(o0) | ((uint)f2bf(o1) << 16);
        ph.y = (uint)f2bf(o2) | ((uint)f2bf(o3) << 16);
        ph.z = (uint)f2bf(o4) | ((uint)f2bf(o5) << 16);
        ph.w = (uint)f2bf(o6) | ((uint)f2bf(o7) << 16);
        // plane [l>>2][node][(l&3)*8 .. +7]
        size_t base = (size_t)(l >> 2) * ((size_t)n * 32) + (size_t)node * 32 + (l & 3) * 8;
        *(uint4*)(ap + base) = ph;
    } else {
        float4 w0 = make_float4(o0, o1, o2, o3);
        float4 w1 = make_float4(o4, o5, o6, o7);
        *(float4*)(out + (size_t)node * HDIM + l * 8)     = w0;
        *(float4*)(out + (size_t)node * HDIM + l * 8 + 4) = w1;
    }
}

// ======================= launch =======================

extern "C" void kernel_launch(void* const* d_in, const int* in_sizes, int n_in,
                              void* d_out, int out_size, void* d_ws, size_t ws_size,
                              hipStream_t stream)
{
    const float* x  = (const float*)d_in[0];
    const int*   ei = (const int*)d_in[1];
    const float* W1 = (const float*)d_in[2];
    const float* b1 = (const float*)d_in[3];
    const float* W2 = (const float*)d_in[4];
    const float* b2 = (const float*)d_in[5];
    const float* W3 = (const float*)d_in[6];
    const float* b3 = (const float*)d_in[7];
    float* out = (float*)d_out;

    const int n = in_sizes[0] / 256;   // IN = 256
    const int E = in_sizes[1] / 2;
    const int* src = ei;
    const int* dst = ei + E;

    // workspace layout (bytes):
    //   dinv @0, cnt @512K, offs @1M, bsum @1.5M, csr @1600K (6.4MB),
    //   rank @8M (6.4MB), wt @14.5M (64KB slot), g @16M (25.7MB), xp @42M (25.7MB)
    char*   ws   = (char*)d_ws;
    float*  dinv = (float*)(ws);
    int*    cnt  = (int*)(ws + (512 << 10));
    int*    offs = (int*)(ws + (1 << 20));
    int*    bsum = (int*)(ws + 1536 * 1024);
    int*    csr  = (int*)(ws + 1600 * 1024);
    int*    rank = (int*)(ws + (size_t)(8 << 20));
    ushort* wt   = (ushort*)(ws + 14848 * 1024);
    ushort* g    = (ushort*)(ws + (size_t)(16 << 20));
    ushort* xp   = (ushort*)(ws + (size_t)(42 << 20));

    dim3 blk(256);
    int ngrid = (n + 255) / 256;
    int egrid = (E + 255) / 256;

    // ---- CSR build + norms ----
    hipMemsetAsync(cnt, 0, (size_t)n * 4, stream);
    k_count<<<egrid, blk, 0, stream>>>(dst, cnt, rank, E);
    k_scan1<<<ngrid, blk, 0, stream>>>(cnt, offs, bsum, dinv, n);
    k_scan2<<<1, 512, 0, stream>>>(bsum, ngrid);
    k_scan3<<<ngrid, blk, 0, stream>>>(offs, bsum, n, E);
    k_fill<<<egrid, blk, 0, stream>>>(src, dst, offs, rank, csr, E);

    int ntiles   = (n + 15) / 16;
    int mm_grid  = (ntiles + 7) / 8;
    int gat_grid = (int)(((size_t)n * 16 + 255) / 256);

    // layer 1 (K=256, fp32 x direct; W in LDS)
    k_prep_w<<<(256 * HDIM + 255) / 256, blk, 0, stream>>>(W1, wt, 256);
    k_mm_f32<<<mm_grid, 512, 0, stream>>>(x, wt, dinv, g, n);
    k_gather<true, true><<<gat_grid, blk, 0, stream>>>(g, csr, offs, dinv, b1, nullptr, xp, n);
    // layer 2 (K=128; W in LDS)
    k_prep_w<<<(128 * HDIM + 255) / 256, blk, 0, stream>>>(W2, wt, 128);
    k_mm<4><<<mm_grid, 512, 0, stream>>>(xp, wt, dinv, g, n);
    k_gather<true, true><<<gat_grid, blk, 0, stream>>>(g, csr, offs, dinv, b2, nullptr, xp, n);
    // layer 3 (K=128; W in LDS)
    k_prep_w<<<(128 * HDIM + 255) / 256, blk, 0, stream>>>(W3, wt, 128);
    k_mm<4><<<mm_grid, 512, 0, stream>>>(xp, wt, dinv, g, n);
    k_gather<false, false><<<gat_grid, blk, 0, stream>>>(g, csr, offs, dinv, b3, out, nullptr, n);
}